// Round 19
// baseline (588.639 us; speedup 1.0000x reference)
//
#include <hip/hip_runtime.h>
#include <hip/hip_cooperative_groups.h>

namespace cg = cooperative_groups;

#define NNODES 50000
#define NEDGES 800000
#define NF 96
#define NF4 24              // float4 per f32 row
#define NBW 4               // nodes per wave (fused): 12500 waves total
#define WPB 4               // waves per block (256 threads); block owns 16 nodes
#define ACC_STRIDE 100      // Acc/T/Ht row stride (floats, 400B, 16B-aligned)
#define NBC 1024            // cooperative grid blocks
#define CHK ((NNODES + NBC - 1) / NBC)   // 49 nodes per coop block

typedef short bf16x8 __attribute__((ext_vector_type(8)));
typedef float f32x4 __attribute__((ext_vector_type(4)));

__device__ inline unsigned pk_bf16(float a, float b) {
    union { __bf16 h[2]; unsigned u; } q;
    q.h[0] = (__bf16)a; q.h[1] = (__bf16)b;
    return q.u;
}
__device__ inline unsigned short bf16_1(float a) {
    union { __bf16 h; unsigned short u; } q;
    q.h = (__bf16)a;
    return q.u;
}
__device__ inline float bf2f_lo(unsigned u) {
    union { unsigned u; float f; } q;
    q.u = u << 16;
    return q.f;
}
__device__ inline float bf2f_hi(unsigned u) {
    union { unsigned u; float f; } q;
    q.u = u & 0xffff0000u;
    return q.f;
}
__device__ inline bf16x8 cvt8(float4 a, float4 b) {
    union { unsigned u[4]; bf16x8 v; } q;
    q.u[0] = pk_bf16(a.x, a.y); q.u[1] = pk_bf16(a.z, a.w);
    q.u[2] = pk_bf16(b.x, b.y); q.u[3] = pk_bf16(b.z, b.w);
    return q.v;
}
__device__ inline int imin(int a, int b) { return a < b ? a : b; }
// ss4 record accessors: {src, dst, e, 0} at int offsets 4p..4p+3
__device__ inline int2 ld_ss(const int* q, int slot) {
    return *reinterpret_cast<const int2*>(q + 4 * slot);
}
__device__ inline int ld_e(const int* q, int slot) { return q[4 * slot + 2]; }

// ---------------------------------------------------------------------------
// build_all (cooperative): W-pack + x-perm + hist | scan | start/cursor | fill
// ---------------------------------------------------------------------------
__global__ __launch_bounds__(256) void build_all(
    const float* __restrict__ We, const float* __restrict__ W1,
    const float* __restrict__ W2, unsigned short* __restrict__ Wep,
    unsigned short* __restrict__ W1p, unsigned short* __restrict__ W2p,
    const int* __restrict__ ei, int* __restrict__ deg,
    const float* __restrict__ x, unsigned* __restrict__ xb2,
    int* __restrict__ bsum, int* __restrict__ start,
    int* __restrict__ cursor, int4* __restrict__ ss4) {
    const int t = threadIdx.x;
    const int gtid = blockIdx.x * 256 + t;
    const int gsz = NBC * 256;

    // ---- phase 0a: pack We/W1/W2 into MFMA B-fragment order (bf16) ----
    for (int i = gtid; i < 3 * 9216; i += gsz) {
        int which = i / 9216, i2 = i % 9216;
        const float* S = (which == 0) ? We : (which == 1) ? W1 : W2;
        unsigned short* D = (which == 0) ? Wep : (which == 1) ? W1p : W2p;
        int f = i2 >> 9, rem = i2 & 511;
        int l = rem >> 3, j = rem & 7;
        int ot = f / 3, kb = f % 3;
        int o = ot * 16 + (l & 15);
        int k = kb * 32 + ((l >> 4) << 3) + j;
        D[i2] = bf16_1(S[o * NF + k]);
    }
    // ---- phase 0b: x -> xb2 gather-friendly bf16 permute ----
    for (int item = gtid; item < NNODES * 48; item += gsz) {
        int n = item / 48, rem = item % 48;
        int l15 = rem / 3, j = rem % 3;
        const float* xr = x + (size_t)n * NF;
        xb2[(size_t)n * 48 + l15 * 3 + j] =
            pk_bf16(xr[32 * j + l15], xr[32 * j + 16 + l15]);
    }
    // ---- phase 0c: dst histogram (fire-and-forget atomics) ----
    for (int e = gtid; e < NEDGES; e += gsz)
        atomicAdd(&deg[ei[NEDGES + e]], 1);

    cg::this_grid().sync();

    // ---- phase 1: per-block partial sum over its CHK-node chunk ----
    __shared__ int red[256];
    const int lo = blockIdx.x * CHK;
    {
        int v = 0;
        if (t < CHK && lo + t < NNODES) v = deg[lo + t];
        red[t] = v;
        __syncthreads();
        for (int off = 128; off; off >>= 1) {
            if (t < off) red[t] += red[t + off];
            __syncthreads();
        }
        if (t == 0) bsum[blockIdx.x] = red[0];
    }

    cg::this_grid().sync();

    // ---- phase 2: every block scans all NBC partials (redundant), then
    //      writes start/cursor for its chunk ----
    __shared__ int sb[256];
    __shared__ int pref[NBC];
    __shared__ int cs[64];
    {
        int a0 = bsum[4 * t], a1 = bsum[4 * t + 1];
        int a2 = bsum[4 * t + 2], a3 = bsum[4 * t + 3];
        int s1 = a0 + a1, s2 = s1 + a2, s3 = s2 + a3;
        sb[t] = s3;
        __syncthreads();
        for (int off = 1; off < 256; off <<= 1) {
            int v = (t >= off) ? sb[t - off] : 0;
            __syncthreads();
            sb[t] += v;
            __syncthreads();
        }
        int base = (t == 0) ? 0 : sb[t - 1];
        pref[4 * t] = base;
        pref[4 * t + 1] = base + a0;
        pref[4 * t + 2] = base + s1;
        pref[4 * t + 3] = base + s2;
        __syncthreads();
    }
    {
        const int bbase = pref[blockIdx.x];
        int d = (t < CHK && lo + t < NNODES) ? deg[lo + t] : 0;
        if (t < 64) cs[t] = (t < CHK) ? d : 0;
        __syncthreads();
        for (int off = 1; off < 64; off <<= 1) {
            int v = (t < 64 && t >= off) ? cs[t - off] : 0;
            __syncthreads();
            if (t < 64) cs[t] += v;
            __syncthreads();
        }
        if (t < CHK && lo + t < NNODES) {
            int excl = bbase + ((t == 0) ? 0 : cs[t - 1]);
            start[lo + t] = excl;
            cursor[lo + t] = excl;
            if (lo + t == NNODES - 1) start[NNODES] = excl + d;
        }
    }

    cg::this_grid().sync();

    // ---- phase 3: fill — ONE aligned 16B record per edge ----
    for (int e = gtid; e < NEDGES; e += gsz) {
        int s = ei[e], d = ei[NEDGES + e];
        int p = atomicAdd(&cursor[d], 1);
        ss4[p] = make_int4(s, d, e, 0);
    }
}

// ---------------------------------------------------------------------------
// Fully fused: edge-GEMM + segment-sum + tail node-MLP (R18 structure).
// R19 deltas: indices from packed ss4 records; setprio(1) around MFMA.
// ---------------------------------------------------------------------------
__global__ __launch_bounds__(256) void fused_all(
    const float* __restrict__ attr, const int* __restrict__ ss4i,
    const int* __restrict__ start, const float* __restrict__ x,
    const unsigned* __restrict__ xb2,
    const unsigned short* __restrict__ Wpack, const float* __restrict__ be,
    const float* __restrict__ epsp,
    const unsigned short* __restrict__ W1p, const float* __restrict__ b1,
    const unsigned short* __restrict__ W2p, const float* __restrict__ b2,
    float* __restrict__ out) {
    __shared__ short Wlds[18 * 64 * 8];               // 18,432 B
    __shared__ float AccT[WPB * NBW * ACC_STRIDE];    //  6,400 B (Acc -> T)
    __shared__ float Ht[16][ACC_STRIDE];              //  6,400 B

    const int t = threadIdx.x;
    {
        const uint4* wsrc = reinterpret_cast<const uint4*>(Wpack);
        uint4* wdst = reinterpret_cast<uint4*>(Wlds);
        for (int i = t; i < 18 * 64; i += 256) wdst[i] = wsrc[i];
        for (int i = t; i < WPB * NBW * ACC_STRIDE; i += 256) AccT[i] = 0.f;
    }
    __syncthreads();

    const int w = t >> 6;
    const int lane = t & 63;
    const int l15 = lane & 15, l4 = lane >> 4;
    const int n0w = (blockIdx.x * WPB + w) * NBW;      // grid exact: < NNODES
    const int s0 = start[n0w], s1 = start[n0w + NBW];
    float* AccW = &AccT[w * NBW * ACC_STRIDE];

    float bias[6];
#pragma unroll
    for (int ot = 0; ot < 6; ++ot) bias[ot] = be[ot * 16 + l15];

    const float4* a4 = reinterpret_cast<const float4*>(attr);
    const int l15x3 = l15 * 3;
    const int nt = (s1 - s0 + 15) >> 4;

    if (nt > 0) {
        const int smax = s1 - 1;

        // ---- prologue: tile 0 data (attr + xe) + tile 1 indices ----
        float4 a_cur[6];
        uint4 xe_cur[4];
        int2 ss_cur[4], ss_nxt[4];
        int ev_nxt;
        {
            int ev0 = ld_e(ss4i, imin(s0 + l15, smax));
            const float4* ar = a4 + (size_t)ev0 * NF4 + l4 * 2;
            a_cur[0] = ar[0];  a_cur[1] = ar[1];
            a_cur[2] = ar[8];  a_cur[3] = ar[9];
            a_cur[4] = ar[16]; a_cur[5] = ar[17];
            ev_nxt = ld_e(ss4i, imin(s0 + 16 + l15, smax));
#pragma unroll
            for (int r = 0; r < 4; ++r) {
                ss_cur[r] = ld_ss(ss4i, imin(s0 + l4 * 4 + r, smax));
                ss_nxt[r] = ld_ss(ss4i, imin(s0 + 16 + l4 * 4 + r, smax));
            }
#pragma unroll
            for (int r = 0; r < 4; ++r)
                xe_cur[r] = *reinterpret_cast<const uint4*>(
                    xb2 + (size_t)ss_cur[r].x * 48 + l15x3);
        }

        for (int tt = 0; tt < nt; ++tt) {
            const int base = s0 + 16 * tt;

            bf16x8 af[3];
            af[0] = cvt8(a_cur[0], a_cur[1]);
            af[1] = cvt8(a_cur[2], a_cur[3]);
            af[2] = cvt8(a_cur[4], a_cur[5]);

            {
                const float4* ar = a4 + (size_t)ev_nxt * NF4 + l4 * 2;
                a_cur[0] = ar[0];  a_cur[1] = ar[1];
                a_cur[2] = ar[8];  a_cur[3] = ar[9];
                a_cur[4] = ar[16]; a_cur[5] = ar[17];
            }
            ev_nxt = ld_e(ss4i, imin(base + 32 + l15, smax));

            int m[4];
#pragma unroll
            for (int r = 0; r < 4; ++r)
                m[r] = ((base + l4 * 4 + r) < s1) ? (ss_cur[r].y - n0w) : -1;

            uint4 xe_nxt[4];
#pragma unroll
            for (int r = 0; r < 4; ++r)
                xe_nxt[r] = *reinterpret_cast<const uint4*>(
                    xb2 + (size_t)ss_nxt[r].x * 48 + l15x3);

#pragma unroll
            for (int r = 0; r < 4; ++r) ss_cur[r] = ss_nxt[r];
#pragma unroll
            for (int r = 0; r < 4; ++r)
                ss_nxt[r] = ld_ss(ss4i, imin(base + 32 + l4 * 4 + r, smax));

            __builtin_amdgcn_s_setprio(1);
            f32x4 acc[6];
#pragma unroll
            for (int ot = 0; ot < 6; ++ot) {
                f32x4 c = {bias[ot], bias[ot], bias[ot], bias[ot]};
#pragma unroll
                for (int kb = 0; kb < 3; ++kb) {
                    bf16x8 bf = *reinterpret_cast<const bf16x8*>(
                        &Wlds[((ot * 3 + kb) * 64 + lane) * 8]);
                    c = __builtin_amdgcn_mfma_f32_16x16x32_bf16(af[kb], bf, c,
                                                                0, 0, 0);
                }
                acc[ot] = c;
            }
            __builtin_amdgcn_s_setprio(0);

            const bool c1 = (m[1] == m[0]);
            const bool c2 = (m[2] == m[1]);
            const bool c3 = (m[3] == m[2]);
#pragma unroll
            for (int ot = 0; ot < 6; ++ot) {
                const int o = ot * 16 + l15;
                const int j = ot >> 1;
                const bool hi = ot & 1;
                float x0 = hi ? bf2f_hi(xe_cur[0][j]) : bf2f_lo(xe_cur[0][j]);
                float x1 = hi ? bf2f_hi(xe_cur[1][j]) : bf2f_lo(xe_cur[1][j]);
                float x2 = hi ? bf2f_hi(xe_cur[2][j]) : bf2f_lo(xe_cur[2][j]);
                float x3 = hi ? bf2f_hi(xe_cur[3][j]) : bf2f_lo(xe_cur[3][j]);
                float v0 = fmaxf(acc[ot][0] + x0, 0.f);
                float v1 = fmaxf(acc[ot][1] + x1, 0.f);
                float v2 = fmaxf(acc[ot][2] + x2, 0.f);
                float v3 = fmaxf(acc[ot][3] + x3, 0.f);
                float run = v0;
                if (!c1) {
                    if (m[0] >= 0) atomicAdd(&AccW[m[0] * ACC_STRIDE + o], run);
                    run = 0.f;
                }
                run += v1;
                if (!c2) {
                    if (m[1] >= 0) atomicAdd(&AccW[m[1] * ACC_STRIDE + o], run);
                    run = 0.f;
                }
                run += v2;
                if (!c3) {
                    if (m[2] >= 0) atomicAdd(&AccW[m[2] * ACC_STRIDE + o], run);
                    run = 0.f;
                }
                run += v3;
                if (m[3] >= 0) atomicAdd(&AccW[m[3] * ACC_STRIDE + o], run);
            }

#pragma unroll
            for (int r = 0; r < 4; ++r) xe_cur[r] = xe_nxt[r];
        }
    }

    // ---- drain this wave's ds_adds; build Ht = (1+eps)x + Acc (fp32 x) ----
    asm volatile("s_waitcnt lgkmcnt(0)" ::: "memory");
    __builtin_amdgcn_sched_barrier(0);
    const float ep = 1.0f + *epsp;
#pragma unroll
    for (int i = 0; i < NBW * NF / 64; ++i) {  // 6
        int item = lane + 64 * i;
        int n = item / NF, f = item % NF;
        Ht[w * NBW + n][f] =
            fmaf(ep, x[(size_t)(n0w + n) * NF + f], AccW[n * ACC_STRIDE + f]);
    }
    __syncthreads();   // Ht complete; Acc dead -> AccT becomes T

    // ---- tail MLP for the block's 16 nodes; waves split ot-slices ----
    const int nb0 = blockIdx.x * (WPB * NBW);

    bf16x8 af1[3];
#pragma unroll
    for (int kb = 0; kb < 3; ++kb) {
        const float4* tr = reinterpret_cast<const float4*>(
            &Ht[l15][kb * 32 + l4 * 8]);
        af1[kb] = cvt8(tr[0], tr[1]);
    }
    for (int ot = w; ot < 6; ot += WPB) {
        float b = b1[ot * 16 + l15];
        f32x4 c = {b, b, b, b};
#pragma unroll
        for (int kb = 0; kb < 3; ++kb) {
            bf16x8 bf = *reinterpret_cast<const bf16x8*>(
                W1p + ((ot * 3 + kb) * 64 + lane) * 8);
            c = __builtin_amdgcn_mfma_f32_16x16x32_bf16(af1[kb], bf, c, 0, 0, 0);
        }
#pragma unroll
        for (int r = 0; r < 4; ++r)
            AccT[(l4 * 4 + r) * ACC_STRIDE + ot * 16 + l15] = fmaxf(c[r], 0.f);
    }
    __syncthreads();   // T complete

    bf16x8 af2[3];
#pragma unroll
    for (int kb = 0; kb < 3; ++kb) {
        const float4* tr = reinterpret_cast<const float4*>(
            &AccT[l15 * ACC_STRIDE + kb * 32 + l4 * 8]);
        af2[kb] = cvt8(tr[0], tr[1]);
    }
    for (int ot = w; ot < 6; ot += WPB) {
        float b = b2[ot * 16 + l15];
        f32x4 c = {b, b, b, b};
#pragma unroll
        for (int kb = 0; kb < 3; ++kb) {
            bf16x8 bf = *reinterpret_cast<const bf16x8*>(
                W2p + ((ot * 3 + kb) * 64 + lane) * 8);
            c = __builtin_amdgcn_mfma_f32_16x16x32_bf16(af2[kb], bf, c, 0, 0, 0);
        }
#pragma unroll
        for (int r = 0; r < 4; ++r)
            out[(size_t)(nb0 + l4 * 4 + r) * NF + ot * 16 + l15] = c[r];
    }
}

// ---------------------------------------------------------------------------
extern "C" void kernel_launch(void* const* d_in, const int* in_sizes, int n_in,
                              void* d_out, int out_size, void* d_ws, size_t ws_size,
                              hipStream_t stream) {
    const float* x   = (const float*)d_in[0];
    const int*   ei  = (const int*)d_in[1];
    const float* ea  = (const float*)d_in[2];
    const float* We  = (const float*)d_in[3];
    const float* be  = (const float*)d_in[4];
    const float* eps = (const float*)d_in[5];
    const float* W1  = (const float*)d_in[6];
    const float* b1  = (const float*)d_in[7];
    const float* W2  = (const float*)d_in[8];
    const float* b2  = (const float*)d_in[9];
    float* out = (float*)d_out;

    // ws layout
    unsigned short* Wep = (unsigned short*)d_ws;         // 9216 bf16
    unsigned short* W1p = Wep + 18 * 64 * 8;             // 9216
    unsigned short* W2p = W1p + 18 * 64 * 8;             // 9216
    unsigned* xb2 = (unsigned*)(W2p + 18 * 64 * 8);      // 50000*48 u32 (+pad)
    int* deg    = (int*)(xb2 + (size_t)NNODES * 48 + 16);// 50000
    int* start  = deg + NNODES;                          // 50001
    int* cursor = start + NNODES + 1;                    // 50000
    int* bsum   = cursor + NNODES;                       // NBC (1024)
    int4* ss4   = (int4*)(bsum + NBC + 12);              // 800000+ int4, 16B-aligned

    hipMemsetAsync(deg, 0, NNODES * sizeof(int), stream);

    void* args[14];
    args[0] = (void*)&We;   args[1] = (void*)&W1;   args[2] = (void*)&W2;
    args[3] = (void*)&Wep;  args[4] = (void*)&W1p;  args[5] = (void*)&W2p;
    args[6] = (void*)&ei;   args[7] = (void*)&deg;  args[8] = (void*)&x;
    args[9] = (void*)&xb2;  args[10] = (void*)&bsum; args[11] = (void*)&start;
    args[12] = (void*)&cursor; args[13] = (void*)&ss4;
    hipLaunchCooperativeKernel((void*)build_all, dim3(NBC), dim3(256), args, 0,
                               stream);

    int nblocks = NNODES / (WPB * NBW);                  // 3125 exact
    fused_all<<<nblocks, 256, 0, stream>>>(ea, (const int*)ss4, start, x, xb2,
                                           Wep, be, eps, W1p, b1, W2p, b2, out);
}

// Round 20
// 258.831 us; speedup vs baseline: 2.2742x; 2.2742x over previous
//
#include <hip/hip_runtime.h>

#define NNODES 50000
#define NEDGES 800000
#define NF 96
#define NF4 24              // float4 per f32 row
#define NBW 4               // nodes per wave (fused): 12500 waves total
#define WPB 4               // waves per block (256 threads); block owns 16 nodes
#define ACC_STRIDE 100      // Acc/T/Ht row stride (floats, 400B, 16B-aligned)

typedef short bf16x8 __attribute__((ext_vector_type(8)));
typedef float f32x4 __attribute__((ext_vector_type(4)));

__device__ inline unsigned pk_bf16(float a, float b) {
    union { __bf16 h[2]; unsigned u; } q;
    q.h[0] = (__bf16)a; q.h[1] = (__bf16)b;
    return q.u;
}
__device__ inline unsigned short bf16_1(float a) {
    union { __bf16 h; unsigned short u; } q;
    q.h = (__bf16)a;
    return q.u;
}
__device__ inline float bf2f_lo(unsigned u) {
    union { unsigned u; float f; } q;
    q.u = u << 16;
    return q.f;
}
__device__ inline float bf2f_hi(unsigned u) {
    union { unsigned u; float f; } q;
    q.u = u & 0xffff0000u;
    return q.f;
}
__device__ inline bf16x8 cvt8(float4 a, float4 b) {
    union { unsigned u[4]; bf16x8 v; } q;
    q.u[0] = pk_bf16(a.x, a.y); q.u[1] = pk_bf16(a.z, a.w);
    q.u[2] = pk_bf16(b.x, b.y); q.u[3] = pk_bf16(b.z, b.w);
    return q.v;
}
__device__ inline int imin(int a, int b) { return a < b ? a : b; }
// ss4 record accessors: {src, dst, e, 0} at int offsets 4p..4p+3
__device__ inline int2 ld_ss(const int* q, int slot) {
    return *reinterpret_cast<const int2*>(q + 4 * slot);
}
__device__ inline int ld_e(const int* q, int slot) { return q[4 * slot + 2]; }

#define HISTB ((NEDGES + 255) / 256)        // 3125
#define XPERMB ((NNODES * 48 + 255) / 256)  // 9375

// ---------------------------------------------------------------------------
// prep: b<3 pack We/W1/W2 into MFMA B-fragment order (bf16);
// b in [3, 3+HISTB): dst histogram; rest: x -> xb2 gather-friendly bf16 perm.
// ---------------------------------------------------------------------------
__global__ __launch_bounds__(256) void prep_hist(
    const float* __restrict__ We, const float* __restrict__ W1,
    const float* __restrict__ W2, unsigned short* __restrict__ Wep,
    unsigned short* __restrict__ W1p, unsigned short* __restrict__ W2p,
    const int* __restrict__ ei, int* __restrict__ deg,
    const float* __restrict__ x, unsigned* __restrict__ xb2) {
    int b = blockIdx.x;
    if (b < 3) {
        const float* S = (b == 0) ? We : (b == 1) ? W1 : W2;
        unsigned short* D = (b == 0) ? Wep : (b == 1) ? W1p : W2p;
        for (int i = threadIdx.x; i < 18 * 64 * 8; i += blockDim.x) {
            int f = i >> 9, rem = i & 511;
            int l = rem >> 3, j = rem & 7;
            int ot = f / 3, kb = f % 3;
            int o = ot * 16 + (l & 15);
            int k = kb * 32 + ((l >> 4) << 3) + j;
            D[i] = bf16_1(S[o * NF + k]);
        }
    } else if (b < 3 + HISTB) {
        int e = (b - 3) * 256 + threadIdx.x;
        if (e < NEDGES) atomicAdd(&deg[ei[NEDGES + e]], 1);
    } else {
        int item = (b - 3 - HISTB) * 256 + threadIdx.x;
        if (item < NNODES * 48) {
            int n = item / 48, rem = item % 48;
            int l15 = rem / 3, j = rem % 3;
            const float* xr = x + (size_t)n * NF;
            xb2[(size_t)n * 48 + l15 * 3 + j] =
                pk_bf16(xr[32 * j + l15], xr[32 * j + 16 + l15]);
        }
    }
}

// ---------------------------------------------------------------------------
// 2-kernel scan (partial sums; write does local scan of partials) + fill
// ---------------------------------------------------------------------------
#define SCAN_BLOCKS 196  // ceil(50000 / 256)

__global__ __launch_bounds__(256) void scan_partial(const int* __restrict__ deg,
                                                    int* __restrict__ bsum) {
    __shared__ int red[256];
    int t = threadIdx.x;
    int i = blockIdx.x * 256 + t;
    red[t] = (i < NNODES) ? deg[i] : 0;
    __syncthreads();
    for (int off = 128; off; off >>= 1) {
        if (t < off) red[t] += red[t + off];
        __syncthreads();
    }
    if (t == 0) bsum[blockIdx.x] = red[0];
}

__global__ __launch_bounds__(256) void scan_write(const int* __restrict__ deg,
                                                  const int* __restrict__ bsum,
                                                  int* __restrict__ start,
                                                  int* __restrict__ cursor) {
    __shared__ int sb[256];
    __shared__ int s[256];
    int t = threadIdx.x;
    sb[t] = (t < SCAN_BLOCKS) ? bsum[t] : 0;
    __syncthreads();
    for (int off = 1; off < 256; off <<= 1) {
        int v = (t >= off) ? sb[t - off] : 0;
        __syncthreads();
        sb[t] += v;
        __syncthreads();
    }
    int bbase = (blockIdx.x == 0) ? 0 : sb[blockIdx.x - 1];

    int i = blockIdx.x * 256 + t;
    int d = (i < NNODES) ? deg[i] : 0;
    s[t] = d;
    __syncthreads();
    for (int off = 1; off < 256; off <<= 1) {
        int v = (t >= off) ? s[t - off] : 0;
        __syncthreads();
        s[t] += v;
        __syncthreads();
    }
    int excl = ((t == 0) ? 0 : s[t - 1]) + bbase;
    if (i < NNODES) {
        start[i] = excl;
        cursor[i] = excl;
        if (i == NNODES - 1) start[NNODES] = excl + d;
    }
}

// fill: ONE aligned 16B record per edge: ss4[p] = {src, dst, e, 0}
__global__ void fill_kernel(const int* __restrict__ ei, int* __restrict__ cursor,
                            int4* __restrict__ ss4) {
    int e = blockIdx.x * blockDim.x + threadIdx.x;
    if (e < NEDGES) {
        int s = ei[e], d = ei[NEDGES + e];
        int p = atomicAdd(&cursor[d], 1);
        ss4[p] = make_int4(s, d, e, 0);
    }
}

// ---------------------------------------------------------------------------
// Fully fused: edge-GEMM + segment-sum + tail node-MLP (R18 structure).
// R20 deltas: indices from packed ss4 records; setprio(1) around MFMA.
// ---------------------------------------------------------------------------
__global__ __launch_bounds__(256) void fused_all(
    const float* __restrict__ attr, const int* __restrict__ ss4i,
    const int* __restrict__ start, const float* __restrict__ x,
    const unsigned* __restrict__ xb2,
    const unsigned short* __restrict__ Wpack, const float* __restrict__ be,
    const float* __restrict__ epsp,
    const unsigned short* __restrict__ W1p, const float* __restrict__ b1,
    const unsigned short* __restrict__ W2p, const float* __restrict__ b2,
    float* __restrict__ out) {
    __shared__ short Wlds[18 * 64 * 8];               // 18,432 B
    __shared__ float AccT[WPB * NBW * ACC_STRIDE];    //  6,400 B (Acc -> T)
    __shared__ float Ht[16][ACC_STRIDE];              //  6,400 B

    const int t = threadIdx.x;
    {
        const uint4* wsrc = reinterpret_cast<const uint4*>(Wpack);
        uint4* wdst = reinterpret_cast<uint4*>(Wlds);
        for (int i = t; i < 18 * 64; i += 256) wdst[i] = wsrc[i];
        for (int i = t; i < WPB * NBW * ACC_STRIDE; i += 256) AccT[i] = 0.f;
    }
    __syncthreads();

    const int w = t >> 6;
    const int lane = t & 63;
    const int l15 = lane & 15, l4 = lane >> 4;
    const int n0w = (blockIdx.x * WPB + w) * NBW;      // grid exact: < NNODES
    const int s0 = start[n0w], s1 = start[n0w + NBW];
    float* AccW = &AccT[w * NBW * ACC_STRIDE];

    float bias[6];
#pragma unroll
    for (int ot = 0; ot < 6; ++ot) bias[ot] = be[ot * 16 + l15];

    const float4* a4 = reinterpret_cast<const float4*>(attr);
    const int l15x3 = l15 * 3;
    const int nt = (s1 - s0 + 15) >> 4;

    if (nt > 0) {
        const int smax = s1 - 1;

        // ---- prologue: tile 0 data (attr + xe) + tile 1 indices ----
        float4 a_cur[6];
        uint4 xe_cur[4];
        int2 ss_cur[4], ss_nxt[4];
        int ev_nxt;
        {
            int ev0 = ld_e(ss4i, imin(s0 + l15, smax));
            const float4* ar = a4 + (size_t)ev0 * NF4 + l4 * 2;
            a_cur[0] = ar[0];  a_cur[1] = ar[1];
            a_cur[2] = ar[8];  a_cur[3] = ar[9];
            a_cur[4] = ar[16]; a_cur[5] = ar[17];
            ev_nxt = ld_e(ss4i, imin(s0 + 16 + l15, smax));
#pragma unroll
            for (int r = 0; r < 4; ++r) {
                ss_cur[r] = ld_ss(ss4i, imin(s0 + l4 * 4 + r, smax));
                ss_nxt[r] = ld_ss(ss4i, imin(s0 + 16 + l4 * 4 + r, smax));
            }
#pragma unroll
            for (int r = 0; r < 4; ++r)
                xe_cur[r] = *reinterpret_cast<const uint4*>(
                    xb2 + (size_t)ss_cur[r].x * 48 + l15x3);
        }

        for (int tt = 0; tt < nt; ++tt) {
            const int base = s0 + 16 * tt;

            bf16x8 af[3];
            af[0] = cvt8(a_cur[0], a_cur[1]);
            af[1] = cvt8(a_cur[2], a_cur[3]);
            af[2] = cvt8(a_cur[4], a_cur[5]);

            {
                const float4* ar = a4 + (size_t)ev_nxt * NF4 + l4 * 2;
                a_cur[0] = ar[0];  a_cur[1] = ar[1];
                a_cur[2] = ar[8];  a_cur[3] = ar[9];
                a_cur[4] = ar[16]; a_cur[5] = ar[17];
            }
            ev_nxt = ld_e(ss4i, imin(base + 32 + l15, smax));

            int m[4];
#pragma unroll
            for (int r = 0; r < 4; ++r)
                m[r] = ((base + l4 * 4 + r) < s1) ? (ss_cur[r].y - n0w) : -1;

            uint4 xe_nxt[4];
#pragma unroll
            for (int r = 0; r < 4; ++r)
                xe_nxt[r] = *reinterpret_cast<const uint4*>(
                    xb2 + (size_t)ss_nxt[r].x * 48 + l15x3);

#pragma unroll
            for (int r = 0; r < 4; ++r) ss_cur[r] = ss_nxt[r];
#pragma unroll
            for (int r = 0; r < 4; ++r)
                ss_nxt[r] = ld_ss(ss4i, imin(base + 32 + l4 * 4 + r, smax));

            __builtin_amdgcn_s_setprio(1);
            f32x4 acc[6];
#pragma unroll
            for (int ot = 0; ot < 6; ++ot) {
                f32x4 c = {bias[ot], bias[ot], bias[ot], bias[ot]};
#pragma unroll
                for (int kb = 0; kb < 3; ++kb) {
                    bf16x8 bf = *reinterpret_cast<const bf16x8*>(
                        &Wlds[((ot * 3 + kb) * 64 + lane) * 8]);
                    c = __builtin_amdgcn_mfma_f32_16x16x32_bf16(af[kb], bf, c,
                                                                0, 0, 0);
                }
                acc[ot] = c;
            }
            __builtin_amdgcn_s_setprio(0);

            const bool c1 = (m[1] == m[0]);
            const bool c2 = (m[2] == m[1]);
            const bool c3 = (m[3] == m[2]);
#pragma unroll
            for (int ot = 0; ot < 6; ++ot) {
                const int o = ot * 16 + l15;
                const int j = ot >> 1;
                const bool hi = ot & 1;
                float x0 = hi ? bf2f_hi(xe_cur[0][j]) : bf2f_lo(xe_cur[0][j]);
                float x1 = hi ? bf2f_hi(xe_cur[1][j]) : bf2f_lo(xe_cur[1][j]);
                float x2 = hi ? bf2f_hi(xe_cur[2][j]) : bf2f_lo(xe_cur[2][j]);
                float x3 = hi ? bf2f_hi(xe_cur[3][j]) : bf2f_lo(xe_cur[3][j]);
                float v0 = fmaxf(acc[ot][0] + x0, 0.f);
                float v1 = fmaxf(acc[ot][1] + x1, 0.f);
                float v2 = fmaxf(acc[ot][2] + x2, 0.f);
                float v3 = fmaxf(acc[ot][3] + x3, 0.f);
                float run = v0;
                if (!c1) {
                    if (m[0] >= 0) atomicAdd(&AccW[m[0] * ACC_STRIDE + o], run);
                    run = 0.f;
                }
                run += v1;
                if (!c2) {
                    if (m[1] >= 0) atomicAdd(&AccW[m[1] * ACC_STRIDE + o], run);
                    run = 0.f;
                }
                run += v2;
                if (!c3) {
                    if (m[2] >= 0) atomicAdd(&AccW[m[2] * ACC_STRIDE + o], run);
                    run = 0.f;
                }
                run += v3;
                if (m[3] >= 0) atomicAdd(&AccW[m[3] * ACC_STRIDE + o], run);
            }

#pragma unroll
            for (int r = 0; r < 4; ++r) xe_cur[r] = xe_nxt[r];
        }
    }

    // ---- drain this wave's ds_adds; build Ht = (1+eps)x + Acc (fp32 x) ----
    asm volatile("s_waitcnt lgkmcnt(0)" ::: "memory");
    __builtin_amdgcn_sched_barrier(0);
    const float ep = 1.0f + *epsp;
#pragma unroll
    for (int i = 0; i < NBW * NF / 64; ++i) {  // 6
        int item = lane + 64 * i;
        int n = item / NF, f = item % NF;
        Ht[w * NBW + n][f] =
            fmaf(ep, x[(size_t)(n0w + n) * NF + f], AccW[n * ACC_STRIDE + f]);
    }
    __syncthreads();   // Ht complete; Acc dead -> AccT becomes T

    // ---- tail MLP for the block's 16 nodes; waves split ot-slices ----
    const int nb0 = blockIdx.x * (WPB * NBW);

    bf16x8 af1[3];
#pragma unroll
    for (int kb = 0; kb < 3; ++kb) {
        const float4* tr = reinterpret_cast<const float4*>(
            &Ht[l15][kb * 32 + l4 * 8]);
        af1[kb] = cvt8(tr[0], tr[1]);
    }
    for (int ot = w; ot < 6; ot += WPB) {
        float b = b1[ot * 16 + l15];
        f32x4 c = {b, b, b, b};
#pragma unroll
        for (int kb = 0; kb < 3; ++kb) {
            bf16x8 bf = *reinterpret_cast<const bf16x8*>(
                W1p + ((ot * 3 + kb) * 64 + lane) * 8);
            c = __builtin_amdgcn_mfma_f32_16x16x32_bf16(af1[kb], bf, c, 0, 0, 0);
        }
#pragma unroll
        for (int r = 0; r < 4; ++r)
            AccT[(l4 * 4 + r) * ACC_STRIDE + ot * 16 + l15] = fmaxf(c[r], 0.f);
    }
    __syncthreads();   // T complete

    bf16x8 af2[3];
#pragma unroll
    for (int kb = 0; kb < 3; ++kb) {
        const float4* tr = reinterpret_cast<const float4*>(
            &AccT[l15 * ACC_STRIDE + kb * 32 + l4 * 8]);
        af2[kb] = cvt8(tr[0], tr[1]);
    }
    for (int ot = w; ot < 6; ot += WPB) {
        float b = b2[ot * 16 + l15];
        f32x4 c = {b, b, b, b};
#pragma unroll
        for (int kb = 0; kb < 3; ++kb) {
            bf16x8 bf = *reinterpret_cast<const bf16x8*>(
                W2p + ((ot * 3 + kb) * 64 + lane) * 8);
            c = __builtin_amdgcn_mfma_f32_16x16x32_bf16(af2[kb], bf, c, 0, 0, 0);
        }
#pragma unroll
        for (int r = 0; r < 4; ++r)
            out[(size_t)(nb0 + l4 * 4 + r) * NF + ot * 16 + l15] = c[r];
    }
}

// ---------------------------------------------------------------------------
extern "C" void kernel_launch(void* const* d_in, const int* in_sizes, int n_in,
                              void* d_out, int out_size, void* d_ws, size_t ws_size,
                              hipStream_t stream) {
    const float* x   = (const float*)d_in[0];
    const int*   ei  = (const int*)d_in[1];
    const float* ea  = (const float*)d_in[2];
    const float* We  = (const float*)d_in[3];
    const float* be  = (const float*)d_in[4];
    const float* eps = (const float*)d_in[5];
    const float* W1  = (const float*)d_in[6];
    const float* b1  = (const float*)d_in[7];
    const float* W2  = (const float*)d_in[8];
    const float* b2  = (const float*)d_in[9];
    float* out = (float*)d_out;

    // ws layout
    unsigned short* Wep = (unsigned short*)d_ws;         // 9216 bf16
    unsigned short* W1p = Wep + 18 * 64 * 8;             // 9216
    unsigned short* W2p = W1p + 18 * 64 * 8;             // 9216
    unsigned* xb2 = (unsigned*)(W2p + 18 * 64 * 8);      // 50000*48 u32 (+pad)
    int* deg    = (int*)(xb2 + (size_t)NNODES * 48 + 16);// 50000
    int* start  = deg + NNODES;                          // 50001
    int* cursor = start + NNODES + 1;                    // 50000
    int* bsum   = cursor + NNODES;                       // 256
    int4* ss4   = (int4*)(bsum + 256 + 12);              // 800000+ int4, 16B-aligned

    hipMemsetAsync(deg, 0, NNODES * sizeof(int), stream);
    prep_hist<<<3 + HISTB + XPERMB, 256, 0, stream>>>(We, W1, W2, Wep, W1p, W2p,
                                                      ei, deg, x, xb2);
    scan_partial<<<SCAN_BLOCKS, 256, 0, stream>>>(deg, bsum);
    scan_write<<<SCAN_BLOCKS, 256, 0, stream>>>(deg, bsum, start, cursor);
    fill_kernel<<<(NEDGES + 255) / 256, 256, 0, stream>>>(ei, cursor, ss4);
    int nblocks = NNODES / (WPB * NBW);                  // 3125 exact
    fused_all<<<nblocks, 256, 0, stream>>>(ea, (const int*)ss4, start, x, xb2,
                                           Wep, be, eps, W1p, b1, W2p, b2, out);
}